// Round 10
// baseline (360.980 us; speedup 1.0000x reference)
//
#include <hip/hip_runtime.h>
#include <math.h>

// ---------------------------------------------------------------------------
// TGN TransformerConv forward — 5 dispatches:
//   memset(counts|dcnt)
//   K1 prep_hist: Wt bf16[448][128] + ball f32[448] + dst histogram with
//                 pos[e] = rank of edge within its dst bucket.
//   K2 scan1:     per-block partial prefix sums -> poffs, bsum; ALSO buckets
//                 nodes by degree (64 bins): pos2[n] = rank within bin.
//   K3 fused:     four block ranges (all depend only on scan1):
//                   [0,QB):   qkv GEMM (reg-A gather + LDS-B dbuf MFMA)
//                   [..+PB):  edge placement ssrc[poffs+pre+pos[e]] = src[e]
//                   [..+FB):  finalize offs = poffs + bsum-prefix
//                   [..+OB):  norder[dbase[bin]+pos2[n]] = n (degree order)
//   K4 attn:      4 nodes/wave via norder (degree-uniform waves -> md==deg,
//                 kills ~30% divergence waste), 8 lanes/head, 1 edge/iter,
//                 2-deep prefetch (R8 loop: VGPR 32; R9's 4-deep ring cost
//                 occupancy 58->32% and regressed), no-max softmax.
// ---------------------------------------------------------------------------

typedef unsigned int uint32;
typedef unsigned short ushort16;
typedef __attribute__((ext_vector_type(8))) short short8;
typedef __attribute__((ext_vector_type(4))) float floatx4;

__device__ __forceinline__ ushort16 f2bf(float f) {
  union { float f; uint32 u; } x; x.f = f;
  uint32 r = x.u + 0x7fffu + ((x.u >> 16) & 1u);   // RNE
  return (ushort16)(r >> 16);
}
__device__ __forceinline__ float bf_lo(uint32 u) {
  union { uint32 u; float f; } x; x.u = u << 16; return x.f;
}
__device__ __forceinline__ float bf_hi(uint32 u) {
  union { uint32 u; float f; } x; x.u = u & 0xffff0000u; return x.f;
}
__device__ __forceinline__ void unpack8(uint4 u, float* f) {
  f[0] = bf_lo(u.x); f[1] = bf_hi(u.x); f[2] = bf_lo(u.y); f[3] = bf_hi(u.y);
  f[4] = bf_lo(u.z); f[5] = bf_hi(u.z); f[6] = bf_lo(u.w); f[7] = bf_hi(u.w);
}
__device__ __forceinline__ short8 pack8s(float4 a, float4 b) {
  union { uint32 u[4]; short8 s; } r;
  r.u[0] = (uint32)f2bf(a.x) | ((uint32)f2bf(a.y) << 16);
  r.u[1] = (uint32)f2bf(a.z) | ((uint32)f2bf(a.w) << 16);
  r.u[2] = (uint32)f2bf(b.x) | ((uint32)f2bf(b.y) << 16);
  r.u[3] = (uint32)f2bf(b.z) | ((uint32)f2bf(b.w) << 16);
  return r.s;
}

// ---- K1: weights->bf16 + biases + histogram with rank recording ------------
__global__ __launch_bounds__(256) void prep_hist_kernel(
    const float* __restrict__ Wq, const float* __restrict__ bq,
    const float* __restrict__ Wk, const float* __restrict__ bk,
    const float* __restrict__ Wv, const float* __restrict__ bv,
    const float* __restrict__ Ws, const float* __restrict__ bs,
    ushort16* __restrict__ Wt, float* __restrict__ ball,
    const int* __restrict__ dstA, int E, int* __restrict__ counts,
    int* __restrict__ pos) {
  int idx = blockIdx.x * 256 + threadIdx.x;
  if (idx < 448 * 128) {
    int n = idx >> 7, k = idx & 127;
    float w;
    if (n < 128)      w = Wq[k * 128 + n];
    else if (n < 256) w = Wk[k * 128 + (n - 128)];
    else if (n < 384) w = Wv[k * 128 + (n - 256)];
    else              w = Ws[k * 64 + (n - 384)];
    Wt[idx] = f2bf(w);
  }
  if (idx < 448) {
    float b;
    if (idx < 128)      b = bq[idx];
    else if (idx < 256) b = bk[idx - 128];
    else if (idx < 384) b = bv[idx - 256];
    else                b = bs[idx - 384];
    ball[idx] = b;
  }
  if (idx < E) pos[idx] = atomicAdd(&counts[dstA[idx]], 1);
}

// ---- K2: per-block scan + degree-bucket ranks ------------------------------
__global__ __launch_bounds__(256) void scan1_kernel(const int* __restrict__ counts,
                                                    int* __restrict__ poffs,
                                                    int* __restrict__ bsum,
                                                    int* __restrict__ dcnt,
                                                    int* __restrict__ pos2, int N) {
  __shared__ int s[256];
  int b = blockIdx.x, t = threadIdx.x;
  int base = b * 4096 + t * 16;
  int vals[16];
  int sum = 0;
#pragma unroll
  for (int i = 0; i < 16; ++i) {
    int idx = base + i;
    vals[i] = (idx < N) ? counts[idx] : 0;
    sum += vals[i];
    if (idx < N) {
      int bin = vals[i] < 63 ? vals[i] : 63;
      pos2[idx] = atomicAdd(&dcnt[bin], 1);
    }
  }
  s[t] = sum;
  __syncthreads();
  for (int off = 1; off < 256; off <<= 1) {
    int vv = (t >= off) ? s[t - off] : 0;
    __syncthreads();
    s[t] += vv;
    __syncthreads();
  }
  int run = (t > 0) ? s[t - 1] : 0;
#pragma unroll
  for (int i = 0; i < 16; ++i) {
    int idx = base + i;
    if (idx < N) poffs[idx] = run;
    run += vals[i];
  }
  if (t == 255) bsum[b] = s[255];
}

// ---- K3: fused qkv GEMM + edge placement + offs finalize + norder ----------
#define LDB 136  // 128+8 pad: ds_read_b128 frags land 2-way = free
__global__ __launch_bounds__(256) void fused_kernel(
    const int* __restrict__ n_id, const float* __restrict__ embtab,
    const float* __restrict__ memtab,
    const ushort16* __restrict__ Wt, const float* __restrict__ ball,
    ushort16* __restrict__ qb, ushort16* __restrict__ kb, ushort16* __restrict__ vb,
    float* __restrict__ outskip, int N,
    const int* __restrict__ srcA, const int* __restrict__ dstA, int E,
    const int* __restrict__ poffs, const int* __restrict__ bsum,
    const int* __restrict__ pos, int* __restrict__ ssrc, int* __restrict__ offs,
    const int* __restrict__ counts, const int* __restrict__ dcnt,
    const int* __restrict__ pos2, int* __restrict__ norder,
    int QB, int PB, int FB) {
  __shared__ ushort16 Bs[2][64 * LDB];
  int b = blockIdx.x;
  int t = threadIdx.x;

  if (b >= QB) {
    if (b < QB + PB) {
      // ---- edge placement: no atomics ----
      int e = (b - QB) * 256 + t;
      if (e < E) {
        int d = dstA[e];
        int blk = d >> 12;
        int add = 0;
        for (int j = 0; j < blk; ++j) add += bsum[j];
        ssrc[poffs[d] + add + pos[e]] = srcA[e];
      }
    } else if (b < QB + PB + FB) {
      // ---- offs finalize ----
      int i = (b - QB - PB) * 256 + t;
      if (i < N) {
        int blk = i >> 12;
        int add = 0;
        for (int j = 0; j < blk; ++j) add += bsum[j];
        offs[i] = poffs[i] + add;
      }
      if (i == 0) offs[N] = E;
    } else {
      // ---- degree-order build: norder[dbase[bin]+pos2[n]] = n ----
      __shared__ int dls[64];
      if (t < 64) dls[t] = dcnt[t];
      __syncthreads();
      int i = (b - QB - PB - FB) * 256 + t;
      if (i < N) {
        int deg = counts[i];
        int bin = deg < 63 ? deg : 63;
        int dbase = 0;
        for (int j = 0; j < bin; ++j) dbase += dls[j];
        norder[dbase + pos2[i]] = i;
      }
    }
    return;
  }

  // ---- qkv GEMM: register-A gather + LDS-B double buffer ----
  int wave = t >> 6, lane = t & 63;
  int lrow = lane & 15, quad = lane >> 4;
  int grow = b * 64 + wave * 16 + lrow;
  bool rvalid = grow < N;
  int srcrow = rvalid ? n_id[grow] : 0;

  const float* embp = embtab + (size_t)srcrow * 64 + quad * 8;
  const float* memp = memtab + (size_t)srcrow * 64 + quad * 8;
  short8 af[4];
  af[0] = pack8s(*(const float4*)(embp), *(const float4*)(embp + 4));
  af[1] = pack8s(*(const float4*)(embp + 32), *(const float4*)(embp + 36));
  af[2] = pack8s(*(const float4*)(memp), *(const float4*)(memp + 4));
  af[3] = pack8s(*(const float4*)(memp + 32), *(const float4*)(memp + 36));

  int sr[4], sc[4];
  uint4 breg[4];
#pragma unroll
  for (int rep = 0; rep < 4; ++rep) {
    int idx = rep * 256 + t;
    sr[rep] = idx >> 4;
    sc[rep] = (idx & 15) * 8;
    breg[rep] = *(const uint4*)(Wt + (size_t)sr[rep] * 128 + sc[rep]);  // ct=0
  }
#pragma unroll
  for (int rep = 0; rep < 4; ++rep)
    *(uint4*)&Bs[0][sr[rep] * LDB + sc[rep]] = breg[rep];
  __syncthreads();

  for (int ct = 0; ct < 7; ++ct) {
    int buf = ct & 1;
    if (ct < 6) {
      const ushort16* wp = Wt + (size_t)(ct + 1) * 8192;
#pragma unroll
      for (int rep = 0; rep < 4; ++rep)
        breg[rep] = *(const uint4*)(wp + (size_t)sr[rep] * 128 + sc[rep]);
    }

    floatx4 acc[4];
#pragma unroll
    for (int j = 0; j < 4; ++j) acc[j] = (floatx4)(0.f);

#pragma unroll
    for (int kk = 0; kk < 4; ++kk) {
      int koff = kk * 32 + quad * 8;
#pragma unroll
      for (int jt = 0; jt < 4; ++jt) {
        short8 bf = *(const short8*)&Bs[buf][(jt * 16 + lrow) * LDB + koff];
        acc[jt] = __builtin_amdgcn_mfma_f32_16x16x32_bf16(bf, af[kk], acc[jt], 0, 0, 0);
      }
    }

    if (rvalid) {
      int col0 = ct * 64;
#pragma unroll
      for (int jt = 0; jt < 4; ++jt) {
        int gcol = col0 + jt * 16 + quad * 4;
        float4 bias = *(const float4*)(ball + gcol);
        float o0 = acc[jt][0] + bias.x;
        float o1 = acc[jt][1] + bias.y;
        float o2 = acc[jt][2] + bias.z;
        float o3 = acc[jt][3] + bias.w;
        if (ct < 6) {
          uint2 pk;
          pk.x = (uint32)f2bf(o0) | ((uint32)f2bf(o1) << 16);
          pk.y = (uint32)f2bf(o2) | ((uint32)f2bf(o3) << 16);
          if (ct < 2)      *(uint2*)(qb + (size_t)grow * 128 + gcol)         = pk;
          else if (ct < 4) *(uint2*)(kb + (size_t)grow * 128 + (gcol - 128)) = pk;
          else             *(uint2*)(vb + (size_t)grow * 128 + (gcol - 256)) = pk;
        } else {
          *(float4*)(outskip + (size_t)grow * 64 + (gcol - 384)) =
              make_float4(o0, o1, o2, o3);
        }
      }
    }

    if (ct < 6) {
#pragma unroll
      for (int rep = 0; rep < 4; ++rep)
        *(uint4*)&Bs[buf ^ 1][sr[rep] * LDB + sc[rep]] = breg[rep];
      __syncthreads();
    }
  }
}

// ---- K4: attention (R8 loop + degree-ordered nodes) ------------------------
// wave = 4 nodes (16 lanes each); 8 lanes/head; lane owns dims 8*l8..8*l8+7.
#define EXPC 0.1803368801111244f  // log2(e)/8
__global__ __launch_bounds__(256) void attn_kernel(
    const ushort16* __restrict__ qb, const ushort16* __restrict__ kb,
    const ushort16* __restrict__ vb, const int* __restrict__ offs,
    const int* __restrict__ ssrc, const int* __restrict__ norder,
    float* __restrict__ out, int N) {
  int tid = threadIdx.x;
  int wave = tid >> 6, lane = tid & 63;
  int nsub = lane >> 4;
  int l16 = lane & 15;
  int head = l16 >> 3;
  int l8 = lane & 7;
  int sidx = (blockIdx.x * 4 + wave) * 4 + nsub;
  bool valid = sidx < N;
  int node = valid ? norder[sidx] : 0;

  int e0 = 0, e1 = 0;
  if (valid) { e0 = offs[node]; e1 = offs[node + 1]; }
  int deg = e1 - e0;
  int md = deg;  // max degree across the wave's 4 nodes (≈deg after sort)
  md = max(md, __shfl_xor(md, 16));
  md = max(md, __shfl_xor(md, 32));

  int hoff = head * 64 + l8 * 8;
  float qf[8];
  {
    uint4 qu = *(const uint4*)(qb + (size_t)node * 128 + hoff);
    unpack8(qu, qf);
  }

  float l = 0.f;
  float a[8];
#pragma unroll
  for (int j = 0; j < 8; ++j) a[j] = 0.f;

  uint4 k0v = make_uint4(0, 0, 0, 0), v0v = k0v, k1v = k0v, v1v = k0v;
  if (md > 0) {
    int e = e0;
    int s = (e < e1) ? ssrc[e] : 0;
    k0v = *(const uint4*)(kb + (size_t)s * 128 + hoff);
    v0v = *(const uint4*)(vb + (size_t)s * 128 + hoff);
  }
  if (md > 1) {
    int e = e0 + 1;
    int s = (e < e1) ? ssrc[e] : 0;
    k1v = *(const uint4*)(kb + (size_t)s * 128 + hoff);
    v1v = *(const uint4*)(vb + (size_t)s * 128 + hoff);
  }

  for (int i = 0; i < md; ++i) {
    uint4 kc = k0v, vc = v0v;
    k0v = k1v; v0v = v1v;
    if (i + 2 < md) {
      int e = e0 + i + 2;
      int s = (e < e1) ? ssrc[e] : 0;
      k1v = *(const uint4*)(kb + (size_t)s * 128 + hoff);
      v1v = *(const uint4*)(vb + (size_t)s * 128 + hoff);
    }
    float kf[8], vf[8];
    unpack8(kc, kf);
    unpack8(vc, vf);
    float p = qf[0] * kf[0];
#pragma unroll
    for (int j = 1; j < 8; ++j) p = fmaf(qf[j], kf[j], p);
    p += __shfl_xor(p, 1);
    p += __shfl_xor(p, 2);
    p += __shfl_xor(p, 4);
    float w = (i < deg) ? exp2f(p * EXPC) : 0.f;
    l += w;
#pragma unroll
    for (int j = 0; j < 8; ++j) a[j] = fmaf(w, vf[j], a[j]);
  }

  float inv = (l > 0.f) ? 0.5f / l : 0.f;
  float r[8];
#pragma unroll
  for (int j = 0; j < 8; ++j) r[j] = a[j] * inv;
  // combine the two heads: lanes l16 and l16^8 hold the same out dims
#pragma unroll
  for (int j = 0; j < 8; ++j) r[j] += __shfl_xor(r[j], 8);

  if (valid && head == 0) {
    float* op = out + (size_t)node * 64 + l8 * 8;
    float4 c0 = *(float4*)op;
    float4 c1 = *(float4*)(op + 4);
    c0.x += r[0]; c0.y += r[1]; c0.z += r[2]; c0.w += r[3];
    c1.x += r[4]; c1.y += r[5]; c1.z += r[6]; c1.w += r[7];
    *(float4*)op = c0;
    *(float4*)(op + 4) = c1;
  }
}

extern "C" void kernel_launch(void* const* d_in, const int* in_sizes, int n_in,
                              void* d_out, int out_size, void* d_ws, size_t ws_size,
                              hipStream_t stream) {
  const int* n_id = (const int*)d_in[0];
  const int* eidx = (const int*)d_in[1];
  const float* memtab = (const float*)d_in[2];
  const float* embtab = (const float*)d_in[3];
  const float* Wq = (const float*)d_in[4];
  const float* bq = (const float*)d_in[5];
  const float* Wk = (const float*)d_in[6];
  const float* bk = (const float*)d_in[7];
  const float* Wv = (const float*)d_in[8];
  const float* bv = (const float*)d_in[9];
  const float* Wskip = (const float*)d_in[10];
  const float* bskip = (const float*)d_in[11];

  int N = in_sizes[0];
  int E = in_sizes[1] / 2;
  const int* srcA = eidx;
  const int* dstA = eidx + E;
  float* out = (float*)d_out;

  char* w = (char*)d_ws;
  ushort16* qb = (ushort16*)w; w += (size_t)N * 128 * 2;
  ushort16* kb = (ushort16*)w; w += (size_t)N * 128 * 2;
  ushort16* vb = (ushort16*)w; w += (size_t)N * 128 * 2;
  ushort16* Wt = (ushort16*)w; w += (size_t)448 * 128 * 2;
  float* ball = (float*)w;     w += (size_t)448 * 4;
  int* counts = (int*)w;       w += (size_t)N * 4;
  int* dcnt = (int*)w;         w += (size_t)64 * 4;   // contiguous with counts
  int* poffs = (int*)w;        w += (size_t)N * 4;
  int* offs = (int*)w;         w += (size_t)(N + 1) * 4;
  int* bsum = (int*)w;         w += (size_t)1024 * 4;
  int* ssrc = (int*)w;         w += (size_t)E * 4;
  int* pos = (int*)w;          w += (size_t)E * 4;
  int* pos2 = (int*)w;         w += (size_t)N * 4;
  int* norder = (int*)w;       w += (size_t)N * 4;

  hipMemsetAsync(counts, 0, (size_t)(N + 64) * 4, stream);  // counts + dcnt

  int k1_threads = (448 * 128 > E) ? 448 * 128 : E;
  prep_hist_kernel<<<(k1_threads + 255) / 256, 256, 0, stream>>>(
      Wq, bq, Wk, bk, Wv, bv, Wskip, bskip, Wt, ball, dstA, E, counts, pos);

  int NB = (N + 4095) / 4096;
  scan1_kernel<<<NB, 256, 0, stream>>>(counts, poffs, bsum, dcnt, pos2, N);

  int QB = (N + 63) / 64;
  int PB = (E + 255) / 256;
  int FB = (N + 255) / 256;
  int OB = (N + 255) / 256;
  fused_kernel<<<QB + PB + FB + OB, 256, 0, stream>>>(
      n_id, embtab, memtab, Wt, ball, qb, kb, vb, out, N,
      srcA, dstA, E, poffs, bsum, pos, ssrc, offs,
      counts, dcnt, pos2, norder, QB, PB, FB);

  attn_kernel<<<(N + 15) / 16, 256, 0, stream>>>(qb, kb, vb, offs, ssrc, norder, out, N);
}

// Round 11
// 258.109 us; speedup vs baseline: 1.3986x; 1.3986x over previous
//
#include <hip/hip_runtime.h>
#include <math.h>

// ---------------------------------------------------------------------------
// TGN TransformerConv forward — 5 dispatches:
//   memset(counts|dcnt)
//   K1 prep_hist: Wt bf16[448][128] + ball f32[448] + dst histogram with
//                 pos[e] = rank of edge within its dst bucket.
//   K2 scan1:     per-block partial prefix sums -> poffs, bsum; ALSO buckets
//                 nodes by degree (64 bins) via per-block LDS histogram +
//                 one global atomic per (block,bin) — R10's per-node global
//                 atomic on 64 bins serialized to 111us (VALUBusy 0.015%).
//   K3 fused:     four block ranges (all depend only on scan1):
//                   [0,QB):   qkv GEMM (reg-A gather + LDS-B dbuf MFMA)
//                   [..+PB):  edge placement ssrc[poffs+pre+pos[e]] = src[e]
//                   [..+FB):  finalize offs = poffs + bsum-prefix
//                   [..+OB):  norder[dbase[bin]+pos2[n]] = n (degree order)
//   K4 attn:      4 nodes/wave via norder (degree-uniform waves -> md≈deg),
//                 8 lanes/head, 1 edge/iter, 2-deep prefetch, no-max softmax.
// ---------------------------------------------------------------------------

typedef unsigned int uint32;
typedef unsigned short ushort16;
typedef __attribute__((ext_vector_type(8))) short short8;
typedef __attribute__((ext_vector_type(4))) float floatx4;

__device__ __forceinline__ ushort16 f2bf(float f) {
  union { float f; uint32 u; } x; x.f = f;
  uint32 r = x.u + 0x7fffu + ((x.u >> 16) & 1u);   // RNE
  return (ushort16)(r >> 16);
}
__device__ __forceinline__ float bf_lo(uint32 u) {
  union { uint32 u; float f; } x; x.u = u << 16; return x.f;
}
__device__ __forceinline__ float bf_hi(uint32 u) {
  union { uint32 u; float f; } x; x.u = u & 0xffff0000u; return x.f;
}
__device__ __forceinline__ void unpack8(uint4 u, float* f) {
  f[0] = bf_lo(u.x); f[1] = bf_hi(u.x); f[2] = bf_lo(u.y); f[3] = bf_hi(u.y);
  f[4] = bf_lo(u.z); f[5] = bf_hi(u.z); f[6] = bf_lo(u.w); f[7] = bf_hi(u.w);
}
__device__ __forceinline__ short8 pack8s(float4 a, float4 b) {
  union { uint32 u[4]; short8 s; } r;
  r.u[0] = (uint32)f2bf(a.x) | ((uint32)f2bf(a.y) << 16);
  r.u[1] = (uint32)f2bf(a.z) | ((uint32)f2bf(a.w) << 16);
  r.u[2] = (uint32)f2bf(b.x) | ((uint32)f2bf(b.y) << 16);
  r.u[3] = (uint32)f2bf(b.z) | ((uint32)f2bf(b.w) << 16);
  return r.s;
}

// ---- K1: weights->bf16 + biases + histogram with rank recording ------------
__global__ __launch_bounds__(256) void prep_hist_kernel(
    const float* __restrict__ Wq, const float* __restrict__ bq,
    const float* __restrict__ Wk, const float* __restrict__ bk,
    const float* __restrict__ Wv, const float* __restrict__ bv,
    const float* __restrict__ Ws, const float* __restrict__ bs,
    ushort16* __restrict__ Wt, float* __restrict__ ball,
    const int* __restrict__ dstA, int E, int* __restrict__ counts,
    int* __restrict__ pos) {
  int idx = blockIdx.x * 256 + threadIdx.x;
  if (idx < 448 * 128) {
    int n = idx >> 7, k = idx & 127;
    float w;
    if (n < 128)      w = Wq[k * 128 + n];
    else if (n < 256) w = Wk[k * 128 + (n - 128)];
    else if (n < 384) w = Wv[k * 128 + (n - 256)];
    else              w = Ws[k * 64 + (n - 384)];
    Wt[idx] = f2bf(w);
  }
  if (idx < 448) {
    float b;
    if (idx < 128)      b = bq[idx];
    else if (idx < 256) b = bk[idx - 128];
    else if (idx < 384) b = bv[idx - 256];
    else                b = bs[idx - 384];
    ball[idx] = b;
  }
  if (idx < E) pos[idx] = atomicAdd(&counts[dstA[idx]], 1);
}

// ---- K2: per-block scan + degree-bucket ranks (LDS histogram) --------------
__global__ __launch_bounds__(256) void scan1_kernel(const int* __restrict__ counts,
                                                    int* __restrict__ poffs,
                                                    int* __restrict__ bsum,
                                                    int* __restrict__ dcnt,
                                                    int* __restrict__ pos2, int N) {
  __shared__ int s[256];
  __shared__ int lh[64];      // per-block degree-bin histogram
  __shared__ int lbase[64];   // this block's base within each global bin
  int b = blockIdx.x, t = threadIdx.x;
  if (t < 64) lh[t] = 0;
  __syncthreads();

  int base = b * 4096 + t * 16;
  int vals[16], bins[16], lrank[16];
  int sum = 0;
#pragma unroll
  for (int i = 0; i < 16; ++i) {
    int idx = base + i;
    vals[i] = (idx < N) ? counts[idx] : 0;
    sum += vals[i];
    if (idx < N) {
      bins[i] = vals[i] < 63 ? vals[i] : 63;
      lrank[i] = atomicAdd(&lh[bins[i]], 1);   // LDS atomic: fast
    }
  }
  __syncthreads();
  if (t < 64) lbase[t] = (lh[t] > 0) ? atomicAdd(&dcnt[t], lh[t]) : 0;
  __syncthreads();
#pragma unroll
  for (int i = 0; i < 16; ++i) {
    int idx = base + i;
    if (idx < N) pos2[idx] = lbase[bins[i]] + lrank[i];
  }

  s[t] = sum;
  __syncthreads();
  for (int off = 1; off < 256; off <<= 1) {
    int vv = (t >= off) ? s[t - off] : 0;
    __syncthreads();
    s[t] += vv;
    __syncthreads();
  }
  int run = (t > 0) ? s[t - 1] : 0;
#pragma unroll
  for (int i = 0; i < 16; ++i) {
    int idx = base + i;
    if (idx < N) poffs[idx] = run;
    run += vals[i];
  }
  if (t == 255) bsum[b] = s[255];
}

// ---- K3: fused qkv GEMM + edge placement + offs finalize + norder ----------
#define LDB 136  // 128+8 pad: ds_read_b128 frags land 2-way = free
__global__ __launch_bounds__(256) void fused_kernel(
    const int* __restrict__ n_id, const float* __restrict__ embtab,
    const float* __restrict__ memtab,
    const ushort16* __restrict__ Wt, const float* __restrict__ ball,
    ushort16* __restrict__ qb, ushort16* __restrict__ kb, ushort16* __restrict__ vb,
    float* __restrict__ outskip, int N,
    const int* __restrict__ srcA, const int* __restrict__ dstA, int E,
    const int* __restrict__ poffs, const int* __restrict__ bsum,
    const int* __restrict__ pos, int* __restrict__ ssrc, int* __restrict__ offs,
    const int* __restrict__ counts, const int* __restrict__ dcnt,
    const int* __restrict__ pos2, int* __restrict__ norder,
    int QB, int PB, int FB) {
  __shared__ ushort16 Bs[2][64 * LDB];
  int b = blockIdx.x;
  int t = threadIdx.x;

  if (b >= QB) {
    if (b < QB + PB) {
      // ---- edge placement: no atomics ----
      int e = (b - QB) * 256 + t;
      if (e < E) {
        int d = dstA[e];
        int blk = d >> 12;
        int add = 0;
        for (int j = 0; j < blk; ++j) add += bsum[j];
        ssrc[poffs[d] + add + pos[e]] = srcA[e];
      }
    } else if (b < QB + PB + FB) {
      // ---- offs finalize ----
      int i = (b - QB - PB) * 256 + t;
      if (i < N) {
        int blk = i >> 12;
        int add = 0;
        for (int j = 0; j < blk; ++j) add += bsum[j];
        offs[i] = poffs[i] + add;
      }
      if (i == 0) offs[N] = E;
    } else {
      // ---- degree-order build: norder[dbase[bin]+pos2[n]] = n ----
      __shared__ int dls[64];
      if (t < 64) dls[t] = dcnt[t];
      __syncthreads();
      int i = (b - QB - PB - FB) * 256 + t;
      if (i < N) {
        int deg = counts[i];
        int bin = deg < 63 ? deg : 63;
        int dbase = 0;
        for (int j = 0; j < bin; ++j) dbase += dls[j];
        norder[dbase + pos2[i]] = i;
      }
    }
    return;
  }

  // ---- qkv GEMM: register-A gather + LDS-B double buffer ----
  int wave = t >> 6, lane = t & 63;
  int lrow = lane & 15, quad = lane >> 4;
  int grow = b * 64 + wave * 16 + lrow;
  bool rvalid = grow < N;
  int srcrow = rvalid ? n_id[grow] : 0;

  const float* embp = embtab + (size_t)srcrow * 64 + quad * 8;
  const float* memp = memtab + (size_t)srcrow * 64 + quad * 8;
  short8 af[4];
  af[0] = pack8s(*(const float4*)(embp), *(const float4*)(embp + 4));
  af[1] = pack8s(*(const float4*)(embp + 32), *(const float4*)(embp + 36));
  af[2] = pack8s(*(const float4*)(memp), *(const float4*)(memp + 4));
  af[3] = pack8s(*(const float4*)(memp + 32), *(const float4*)(memp + 36));

  int sr[4], sc[4];
  uint4 breg[4];
#pragma unroll
  for (int rep = 0; rep < 4; ++rep) {
    int idx = rep * 256 + t;
    sr[rep] = idx >> 4;
    sc[rep] = (idx & 15) * 8;
    breg[rep] = *(const uint4*)(Wt + (size_t)sr[rep] * 128 + sc[rep]);  // ct=0
  }
#pragma unroll
  for (int rep = 0; rep < 4; ++rep)
    *(uint4*)&Bs[0][sr[rep] * LDB + sc[rep]] = breg[rep];
  __syncthreads();

  for (int ct = 0; ct < 7; ++ct) {
    int buf = ct & 1;
    if (ct < 6) {
      const ushort16* wp = Wt + (size_t)(ct + 1) * 8192;
#pragma unroll
      for (int rep = 0; rep < 4; ++rep)
        breg[rep] = *(const uint4*)(wp + (size_t)sr[rep] * 128 + sc[rep]);
    }

    floatx4 acc[4];
#pragma unroll
    for (int j = 0; j < 4; ++j) acc[j] = (floatx4)(0.f);

#pragma unroll
    for (int kk = 0; kk < 4; ++kk) {
      int koff = kk * 32 + quad * 8;
#pragma unroll
      for (int jt = 0; jt < 4; ++jt) {
        short8 bf = *(const short8*)&Bs[buf][(jt * 16 + lrow) * LDB + koff];
        acc[jt] = __builtin_amdgcn_mfma_f32_16x16x32_bf16(bf, af[kk], acc[jt], 0, 0, 0);
      }
    }

    if (rvalid) {
      int col0 = ct * 64;
#pragma unroll
      for (int jt = 0; jt < 4; ++jt) {
        int gcol = col0 + jt * 16 + quad * 4;
        float4 bias = *(const float4*)(ball + gcol);
        float o0 = acc[jt][0] + bias.x;
        float o1 = acc[jt][1] + bias.y;
        float o2 = acc[jt][2] + bias.z;
        float o3 = acc[jt][3] + bias.w;
        if (ct < 6) {
          uint2 pk;
          pk.x = (uint32)f2bf(o0) | ((uint32)f2bf(o1) << 16);
          pk.y = (uint32)f2bf(o2) | ((uint32)f2bf(o3) << 16);
          if (ct < 2)      *(uint2*)(qb + (size_t)grow * 128 + gcol)         = pk;
          else if (ct < 4) *(uint2*)(kb + (size_t)grow * 128 + (gcol - 128)) = pk;
          else             *(uint2*)(vb + (size_t)grow * 128 + (gcol - 256)) = pk;
        } else {
          *(float4*)(outskip + (size_t)grow * 64 + (gcol - 384)) =
              make_float4(o0, o1, o2, o3);
        }
      }
    }

    if (ct < 6) {
#pragma unroll
      for (int rep = 0; rep < 4; ++rep)
        *(uint4*)&Bs[buf ^ 1][sr[rep] * LDB + sc[rep]] = breg[rep];
      __syncthreads();
    }
  }
}

// ---- K4: attention (R8 loop + degree-ordered nodes) ------------------------
// wave = 4 nodes (16 lanes each); 8 lanes/head; lane owns dims 8*l8..8*l8+7.
#define EXPC 0.1803368801111244f  // log2(e)/8
__global__ __launch_bounds__(256) void attn_kernel(
    const ushort16* __restrict__ qb, const ushort16* __restrict__ kb,
    const ushort16* __restrict__ vb, const int* __restrict__ offs,
    const int* __restrict__ ssrc, const int* __restrict__ norder,
    float* __restrict__ out, int N) {
  int tid = threadIdx.x;
  int wave = tid >> 6, lane = tid & 63;
  int nsub = lane >> 4;
  int l16 = lane & 15;
  int head = l16 >> 3;
  int l8 = lane & 7;
  int sidx = (blockIdx.x * 4 + wave) * 4 + nsub;
  bool valid = sidx < N;
  int node = valid ? norder[sidx] : 0;

  int e0 = 0, e1 = 0;
  if (valid) { e0 = offs[node]; e1 = offs[node + 1]; }
  int deg = e1 - e0;
  int md = deg;  // max degree across the wave's 4 nodes (≈deg after sort)
  md = max(md, __shfl_xor(md, 16));
  md = max(md, __shfl_xor(md, 32));

  int hoff = head * 64 + l8 * 8;
  float qf[8];
  {
    uint4 qu = *(const uint4*)(qb + (size_t)node * 128 + hoff);
    unpack8(qu, qf);
  }

  float l = 0.f;
  float a[8];
#pragma unroll
  for (int j = 0; j < 8; ++j) a[j] = 0.f;

  uint4 k0v = make_uint4(0, 0, 0, 0), v0v = k0v, k1v = k0v, v1v = k0v;
  if (md > 0) {
    int e = e0;
    int s = (e < e1) ? ssrc[e] : 0;
    k0v = *(const uint4*)(kb + (size_t)s * 128 + hoff);
    v0v = *(const uint4*)(vb + (size_t)s * 128 + hoff);
  }
  if (md > 1) {
    int e = e0 + 1;
    int s = (e < e1) ? ssrc[e] : 0;
    k1v = *(const uint4*)(kb + (size_t)s * 128 + hoff);
    v1v = *(const uint4*)(vb + (size_t)s * 128 + hoff);
  }

  for (int i = 0; i < md; ++i) {
    uint4 kc = k0v, vc = v0v;
    k0v = k1v; v0v = v1v;
    if (i + 2 < md) {
      int e = e0 + i + 2;
      int s = (e < e1) ? ssrc[e] : 0;
      k1v = *(const uint4*)(kb + (size_t)s * 128 + hoff);
      v1v = *(const uint4*)(vb + (size_t)s * 128 + hoff);
    }
    float kf[8], vf[8];
    unpack8(kc, kf);
    unpack8(vc, vf);
    float p = qf[0] * kf[0];
#pragma unroll
    for (int j = 1; j < 8; ++j) p = fmaf(qf[j], kf[j], p);
    p += __shfl_xor(p, 1);
    p += __shfl_xor(p, 2);
    p += __shfl_xor(p, 4);
    float w = (i < deg) ? exp2f(p * EXPC) : 0.f;
    l += w;
#pragma unroll
    for (int j = 0; j < 8; ++j) a[j] = fmaf(w, vf[j], a[j]);
  }

  float inv = (l > 0.f) ? 0.5f / l : 0.f;
  float r[8];
#pragma unroll
  for (int j = 0; j < 8; ++j) r[j] = a[j] * inv;
  // combine the two heads: lanes l16 and l16^8 hold the same out dims
#pragma unroll
  for (int j = 0; j < 8; ++j) r[j] += __shfl_xor(r[j], 8);

  if (valid && head == 0) {
    float* op = out + (size_t)node * 64 + l8 * 8;
    float4 c0 = *(float4*)op;
    float4 c1 = *(float4*)(op + 4);
    c0.x += r[0]; c0.y += r[1]; c0.z += r[2]; c0.w += r[3];
    c1.x += r[4]; c1.y += r[5]; c1.z += r[6]; c1.w += r[7];
    *(float4*)op = c0;
    *(float4*)(op + 4) = c1;
  }
}

extern "C" void kernel_launch(void* const* d_in, const int* in_sizes, int n_in,
                              void* d_out, int out_size, void* d_ws, size_t ws_size,
                              hipStream_t stream) {
  const int* n_id = (const int*)d_in[0];
  const int* eidx = (const int*)d_in[1];
  const float* memtab = (const float*)d_in[2];
  const float* embtab = (const float*)d_in[3];
  const float* Wq = (const float*)d_in[4];
  const float* bq = (const float*)d_in[5];
  const float* Wk = (const float*)d_in[6];
  const float* bk = (const float*)d_in[7];
  const float* Wv = (const float*)d_in[8];
  const float* bv = (const float*)d_in[9];
  const float* Wskip = (const float*)d_in[10];
  const float* bskip = (const float*)d_in[11];

  int N = in_sizes[0];
  int E = in_sizes[1] / 2;
  const int* srcA = eidx;
  const int* dstA = eidx + E;
  float* out = (float*)d_out;

  char* w = (char*)d_ws;
  ushort16* qb = (ushort16*)w; w += (size_t)N * 128 * 2;
  ushort16* kb = (ushort16*)w; w += (size_t)N * 128 * 2;
  ushort16* vb = (ushort16*)w; w += (size_t)N * 128 * 2;
  ushort16* Wt = (ushort16*)w; w += (size_t)448 * 128 * 2;
  float* ball = (float*)w;     w += (size_t)448 * 4;
  int* counts = (int*)w;       w += (size_t)N * 4;
  int* dcnt = (int*)w;         w += (size_t)64 * 4;   // contiguous with counts
  int* poffs = (int*)w;        w += (size_t)N * 4;
  int* offs = (int*)w;         w += (size_t)(N + 1) * 4;
  int* bsum = (int*)w;         w += (size_t)1024 * 4;
  int* ssrc = (int*)w;         w += (size_t)E * 4;
  int* pos = (int*)w;          w += (size_t)E * 4;
  int* pos2 = (int*)w;         w += (size_t)N * 4;
  int* norder = (int*)w;       w += (size_t)N * 4;

  hipMemsetAsync(counts, 0, (size_t)(N + 64) * 4, stream);  // counts + dcnt

  int k1_threads = (448 * 128 > E) ? 448 * 128 : E;
  prep_hist_kernel<<<(k1_threads + 255) / 256, 256, 0, stream>>>(
      Wq, bq, Wk, bk, Wv, bv, Wskip, bskip, Wt, ball, dstA, E, counts, pos);

  int NB = (N + 4095) / 4096;
  scan1_kernel<<<NB, 256, 0, stream>>>(counts, poffs, bsum, dcnt, pos2, N);

  int QB = (N + 63) / 64;
  int PB = (E + 255) / 256;
  int FB = (N + 255) / 256;
  int OB = (N + 255) / 256;
  fused_kernel<<<QB + PB + FB + OB, 256, 0, stream>>>(
      n_id, embtab, memtab, Wt, ball, qb, kb, vb, out, N,
      srcA, dstA, E, poffs, bsum, pos, ssrc, offs,
      counts, dcnt, pos2, norder, QB, PB, FB);

  attn_kernel<<<(N + 15) / 16, 256, 0, stream>>>(qb, kb, vb, offs, ssrc, norder, out, N);
}

// Round 12
// 247.640 us; speedup vs baseline: 1.4577x; 1.0423x over previous
//
#include <hip/hip_runtime.h>
#include <math.h>

// ---------------------------------------------------------------------------
// TGN TransformerConv forward — 5 dispatches:
//   memset(counts)
//   K1 prep_hist: Wt bf16[448][128] + ball f32[448] + dst histogram with
//                 pos[e] = rank of edge within its dst bucket.
//   K2 scan1:     per-block partial prefix sums -> poffs, bsum
//   K3 fused:     three block ranges (all depend only on scan1):
//                   [0,QB):   qkv GEMM (reg-A gather + LDS-B dbuf MFMA)
//                   [..+PB):  edge placement ssrc[poffs+pre+pos[e]] = src[e]
//                   [..+FB):  finalize offs = poffs + bsum-prefix
//   K4 attn:      4 consecutive nodes/wave, 8 lanes/head, 1 edge/iter,
//                 2-deep prefetch, no-max softmax (|score|<~6).
// R11 post-mortem: degree-sorted attn (norder) cut VALU 42->33% but broke
// q/out locality (FETCH +6MB) — net loss vs sequential order; removed.
// R9 post-mortem: 4-deep ring cost occupancy 58->32%; 2-deep is the optimum.
// ---------------------------------------------------------------------------

typedef unsigned int uint32;
typedef unsigned short ushort16;
typedef __attribute__((ext_vector_type(8))) short short8;
typedef __attribute__((ext_vector_type(4))) float floatx4;

__device__ __forceinline__ ushort16 f2bf(float f) {
  union { float f; uint32 u; } x; x.f = f;
  uint32 r = x.u + 0x7fffu + ((x.u >> 16) & 1u);   // RNE
  return (ushort16)(r >> 16);
}
__device__ __forceinline__ float bf_lo(uint32 u) {
  union { uint32 u; float f; } x; x.u = u << 16; return x.f;
}
__device__ __forceinline__ float bf_hi(uint32 u) {
  union { uint32 u; float f; } x; x.u = u & 0xffff0000u; return x.f;
}
__device__ __forceinline__ void unpack8(uint4 u, float* f) {
  f[0] = bf_lo(u.x); f[1] = bf_hi(u.x); f[2] = bf_lo(u.y); f[3] = bf_hi(u.y);
  f[4] = bf_lo(u.z); f[5] = bf_hi(u.z); f[6] = bf_lo(u.w); f[7] = bf_hi(u.w);
}
__device__ __forceinline__ short8 pack8s(float4 a, float4 b) {
  union { uint32 u[4]; short8 s; } r;
  r.u[0] = (uint32)f2bf(a.x) | ((uint32)f2bf(a.y) << 16);
  r.u[1] = (uint32)f2bf(a.z) | ((uint32)f2bf(a.w) << 16);
  r.u[2] = (uint32)f2bf(b.x) | ((uint32)f2bf(b.y) << 16);
  r.u[3] = (uint32)f2bf(b.z) | ((uint32)f2bf(b.w) << 16);
  return r.s;
}

// ---- K1: weights->bf16 + biases + histogram with rank recording ------------
__global__ __launch_bounds__(256) void prep_hist_kernel(
    const float* __restrict__ Wq, const float* __restrict__ bq,
    const float* __restrict__ Wk, const float* __restrict__ bk,
    const float* __restrict__ Wv, const float* __restrict__ bv,
    const float* __restrict__ Ws, const float* __restrict__ bs,
    ushort16* __restrict__ Wt, float* __restrict__ ball,
    const int* __restrict__ dstA, int E, int* __restrict__ counts,
    int* __restrict__ pos) {
  int idx = blockIdx.x * 256 + threadIdx.x;
  if (idx < 448 * 128) {
    int n = idx >> 7, k = idx & 127;
    float w;
    if (n < 128)      w = Wq[k * 128 + n];
    else if (n < 256) w = Wk[k * 128 + (n - 128)];
    else if (n < 384) w = Wv[k * 128 + (n - 256)];
    else              w = Ws[k * 64 + (n - 384)];
    Wt[idx] = f2bf(w);
  }
  if (idx < 448) {
    float b;
    if (idx < 128)      b = bq[idx];
    else if (idx < 256) b = bk[idx - 128];
    else if (idx < 384) b = bv[idx - 256];
    else                b = bs[idx - 384];
    ball[idx] = b;
  }
  if (idx < E) pos[idx] = atomicAdd(&counts[dstA[idx]], 1);
}

// ---- K2: per-block scan (4096 elems/block); poffs partial, bsum raw --------
__global__ __launch_bounds__(256) void scan1_kernel(const int* __restrict__ counts,
                                                    int* __restrict__ poffs,
                                                    int* __restrict__ bsum, int N) {
  __shared__ int s[256];
  int b = blockIdx.x, t = threadIdx.x;
  int base = b * 4096 + t * 16;
  int vals[16];
  int sum = 0;
#pragma unroll
  for (int i = 0; i < 16; ++i) {
    int idx = base + i;
    vals[i] = (idx < N) ? counts[idx] : 0;
    sum += vals[i];
  }
  s[t] = sum;
  __syncthreads();
  for (int off = 1; off < 256; off <<= 1) {
    int vv = (t >= off) ? s[t - off] : 0;
    __syncthreads();
    s[t] += vv;
    __syncthreads();
  }
  int run = (t > 0) ? s[t - 1] : 0;
#pragma unroll
  for (int i = 0; i < 16; ++i) {
    int idx = base + i;
    if (idx < N) poffs[idx] = run;
    run += vals[i];
  }
  if (t == 255) bsum[b] = s[255];
}

// ---- K3: fused qkv GEMM + edge placement + offs finalize -------------------
#define LDB 136  // 128+8 pad: ds_read_b128 frags land 2-way = free
__global__ __launch_bounds__(256) void fused_kernel(
    const int* __restrict__ n_id, const float* __restrict__ embtab,
    const float* __restrict__ memtab,
    const ushort16* __restrict__ Wt, const float* __restrict__ ball,
    ushort16* __restrict__ qb, ushort16* __restrict__ kb, ushort16* __restrict__ vb,
    float* __restrict__ outskip, int N,
    const int* __restrict__ srcA, const int* __restrict__ dstA, int E,
    const int* __restrict__ poffs, const int* __restrict__ bsum,
    const int* __restrict__ pos, int* __restrict__ ssrc, int* __restrict__ offs,
    int QB, int PB) {
  __shared__ ushort16 Bs[2][64 * LDB];
  int b = blockIdx.x;
  int t = threadIdx.x;

  if (b >= QB) {
    if (b < QB + PB) {
      // ---- edge placement: no atomics ----
      int e = (b - QB) * 256 + t;
      if (e < E) {
        int d = dstA[e];
        int blk = d >> 12;
        int add = 0;
        for (int j = 0; j < blk; ++j) add += bsum[j];
        ssrc[poffs[d] + add + pos[e]] = srcA[e];
      }
    } else {
      // ---- offs finalize ----
      int i = (b - QB - PB) * 256 + t;
      if (i < N) {
        int blk = i >> 12;
        int add = 0;
        for (int j = 0; j < blk; ++j) add += bsum[j];
        offs[i] = poffs[i] + add;
      }
      if (i == 0) offs[N] = E;
    }
    return;
  }

  // ---- qkv GEMM: register-A gather + LDS-B double buffer ----
  int wave = t >> 6, lane = t & 63;
  int lrow = lane & 15, quad = lane >> 4;
  int grow = b * 64 + wave * 16 + lrow;
  bool rvalid = grow < N;
  int srcrow = rvalid ? n_id[grow] : 0;

  const float* embp = embtab + (size_t)srcrow * 64 + quad * 8;
  const float* memp = memtab + (size_t)srcrow * 64 + quad * 8;
  short8 af[4];
  af[0] = pack8s(*(const float4*)(embp), *(const float4*)(embp + 4));
  af[1] = pack8s(*(const float4*)(embp + 32), *(const float4*)(embp + 36));
  af[2] = pack8s(*(const float4*)(memp), *(const float4*)(memp + 4));
  af[3] = pack8s(*(const float4*)(memp + 32), *(const float4*)(memp + 36));

  int sr[4], sc[4];
  uint4 breg[4];
#pragma unroll
  for (int rep = 0; rep < 4; ++rep) {
    int idx = rep * 256 + t;
    sr[rep] = idx >> 4;
    sc[rep] = (idx & 15) * 8;
    breg[rep] = *(const uint4*)(Wt + (size_t)sr[rep] * 128 + sc[rep]);  // ct=0
  }
#pragma unroll
  for (int rep = 0; rep < 4; ++rep)
    *(uint4*)&Bs[0][sr[rep] * LDB + sc[rep]] = breg[rep];
  __syncthreads();

  for (int ct = 0; ct < 7; ++ct) {
    int buf = ct & 1;
    if (ct < 6) {
      const ushort16* wp = Wt + (size_t)(ct + 1) * 8192;
#pragma unroll
      for (int rep = 0; rep < 4; ++rep)
        breg[rep] = *(const uint4*)(wp + (size_t)sr[rep] * 128 + sc[rep]);
    }

    floatx4 acc[4];
#pragma unroll
    for (int j = 0; j < 4; ++j) acc[j] = (floatx4)(0.f);

#pragma unroll
    for (int kk = 0; kk < 4; ++kk) {
      int koff = kk * 32 + quad * 8;
#pragma unroll
      for (int jt = 0; jt < 4; ++jt) {
        short8 bf = *(const short8*)&Bs[buf][(jt * 16 + lrow) * LDB + koff];
        acc[jt] = __builtin_amdgcn_mfma_f32_16x16x32_bf16(bf, af[kk], acc[jt], 0, 0, 0);
      }
    }

    if (rvalid) {
      int col0 = ct * 64;
#pragma unroll
      for (int jt = 0; jt < 4; ++jt) {
        int gcol = col0 + jt * 16 + quad * 4;
        float4 bias = *(const float4*)(ball + gcol);
        float o0 = acc[jt][0] + bias.x;
        float o1 = acc[jt][1] + bias.y;
        float o2 = acc[jt][2] + bias.z;
        float o3 = acc[jt][3] + bias.w;
        if (ct < 6) {
          uint2 pk;
          pk.x = (uint32)f2bf(o0) | ((uint32)f2bf(o1) << 16);
          pk.y = (uint32)f2bf(o2) | ((uint32)f2bf(o3) << 16);
          if (ct < 2)      *(uint2*)(qb + (size_t)grow * 128 + gcol)         = pk;
          else if (ct < 4) *(uint2*)(kb + (size_t)grow * 128 + (gcol - 128)) = pk;
          else             *(uint2*)(vb + (size_t)grow * 128 + (gcol - 256)) = pk;
        } else {
          *(float4*)(outskip + (size_t)grow * 64 + (gcol - 384)) =
              make_float4(o0, o1, o2, o3);
        }
      }
    }

    if (ct < 6) {
#pragma unroll
      for (int rep = 0; rep < 4; ++rep)
        *(uint4*)&Bs[buf ^ 1][sr[rep] * LDB + sc[rep]] = breg[rep];
      __syncthreads();
    }
  }
}

// ---- K4: attention (R8 loop, sequential node order) ------------------------
// wave = 4 consecutive nodes (16 lanes each); 8 lanes/head; lane owns dims
// 8*l8..8*l8+7 (uint4 = 8 bf16). No max-tracking (|score| <~ 6).
#define EXPC 0.1803368801111244f  // log2(e)/8
__global__ __launch_bounds__(256) void attn_kernel(
    const ushort16* __restrict__ qb, const ushort16* __restrict__ kb,
    const ushort16* __restrict__ vb, const int* __restrict__ offs,
    const int* __restrict__ ssrc, float* __restrict__ out, int N) {
  int tid = threadIdx.x;
  int wave = tid >> 6, lane = tid & 63;
  int nsub = lane >> 4;
  int l16 = lane & 15;
  int head = l16 >> 3;
  int l8 = lane & 7;
  int node = (blockIdx.x * 4 + wave) * 4 + nsub;
  bool valid = node < N;
  int nodeC = valid ? node : 0;

  int e0 = 0, e1 = 0;
  if (valid) { e0 = offs[node]; e1 = offs[node + 1]; }
  int deg = e1 - e0;
  int md = deg;  // max degree across the wave's 4 nodes
  md = max(md, __shfl_xor(md, 16));
  md = max(md, __shfl_xor(md, 32));

  int hoff = head * 64 + l8 * 8;
  float qf[8];
  {
    uint4 qu = *(const uint4*)(qb + (size_t)nodeC * 128 + hoff);
    unpack8(qu, qf);
  }

  float l = 0.f;
  float a[8];
#pragma unroll
  for (int j = 0; j < 8; ++j) a[j] = 0.f;

  uint4 k0v = make_uint4(0, 0, 0, 0), v0v = k0v, k1v = k0v, v1v = k0v;
  if (md > 0) {
    int e = e0;
    int s = (e < e1) ? ssrc[e] : 0;
    k0v = *(const uint4*)(kb + (size_t)s * 128 + hoff);
    v0v = *(const uint4*)(vb + (size_t)s * 128 + hoff);
  }
  if (md > 1) {
    int e = e0 + 1;
    int s = (e < e1) ? ssrc[e] : 0;
    k1v = *(const uint4*)(kb + (size_t)s * 128 + hoff);
    v1v = *(const uint4*)(vb + (size_t)s * 128 + hoff);
  }

  for (int i = 0; i < md; ++i) {
    uint4 kc = k0v, vc = v0v;
    k0v = k1v; v0v = v1v;
    if (i + 2 < md) {
      int e = e0 + i + 2;
      int s = (e < e1) ? ssrc[e] : 0;
      k1v = *(const uint4*)(kb + (size_t)s * 128 + hoff);
      v1v = *(const uint4*)(vb + (size_t)s * 128 + hoff);
    }
    float kf[8], vf[8];
    unpack8(kc, kf);
    unpack8(vc, vf);
    float p = qf[0] * kf[0];
#pragma unroll
    for (int j = 1; j < 8; ++j) p = fmaf(qf[j], kf[j], p);
    p += __shfl_xor(p, 1);
    p += __shfl_xor(p, 2);
    p += __shfl_xor(p, 4);
    float w = (i < deg) ? exp2f(p * EXPC) : 0.f;
    l += w;
#pragma unroll
    for (int j = 0; j < 8; ++j) a[j] = fmaf(w, vf[j], a[j]);
  }

  float inv = (l > 0.f) ? 0.5f / l : 0.f;
  float r[8];
#pragma unroll
  for (int j = 0; j < 8; ++j) r[j] = a[j] * inv;
  // combine the two heads: lanes l16 and l16^8 hold the same out dims
#pragma unroll
  for (int j = 0; j < 8; ++j) r[j] += __shfl_xor(r[j], 8);

  if (valid && head == 0) {
    float* op = out + (size_t)node * 64 + l8 * 8;
    float4 c0 = *(float4*)op;
    float4 c1 = *(float4*)(op + 4);
    c0.x += r[0]; c0.y += r[1]; c0.z += r[2]; c0.w += r[3];
    c1.x += r[4]; c1.y += r[5]; c1.z += r[6]; c1.w += r[7];
    *(float4*)op = c0;
    *(float4*)(op + 4) = c1;
  }
}

extern "C" void kernel_launch(void* const* d_in, const int* in_sizes, int n_in,
                              void* d_out, int out_size, void* d_ws, size_t ws_size,
                              hipStream_t stream) {
  const int* n_id = (const int*)d_in[0];
  const int* eidx = (const int*)d_in[1];
  const float* memtab = (const float*)d_in[2];
  const float* embtab = (const float*)d_in[3];
  const float* Wq = (const float*)d_in[4];
  const float* bq = (const float*)d_in[5];
  const float* Wk = (const float*)d_in[6];
  const float* bk = (const float*)d_in[7];
  const float* Wv = (const float*)d_in[8];
  const float* bv = (const float*)d_in[9];
  const float* Wskip = (const float*)d_in[10];
  const float* bskip = (const float*)d_in[11];

  int N = in_sizes[0];
  int E = in_sizes[1] / 2;
  const int* srcA = eidx;
  const int* dstA = eidx + E;
  float* out = (float*)d_out;

  char* w = (char*)d_ws;
  ushort16* qb = (ushort16*)w; w += (size_t)N * 128 * 2;
  ushort16* kb = (ushort16*)w; w += (size_t)N * 128 * 2;
  ushort16* vb = (ushort16*)w; w += (size_t)N * 128 * 2;
  ushort16* Wt = (ushort16*)w; w += (size_t)448 * 128 * 2;
  float* ball = (float*)w;     w += (size_t)448 * 4;
  int* counts = (int*)w;       w += (size_t)N * 4;
  int* poffs = (int*)w;        w += (size_t)N * 4;
  int* offs = (int*)w;         w += (size_t)(N + 1) * 4;
  int* bsum = (int*)w;         w += (size_t)1024 * 4;
  int* ssrc = (int*)w;         w += (size_t)E * 4;
  int* pos = (int*)w;          w += (size_t)E * 4;

  hipMemsetAsync(counts, 0, (size_t)N * 4, stream);

  int k1_threads = (448 * 128 > E) ? 448 * 128 : E;
  prep_hist_kernel<<<(k1_threads + 255) / 256, 256, 0, stream>>>(
      Wq, bq, Wk, bk, Wv, bv, Wskip, bskip, Wt, ball, dstA, E, counts, pos);

  int NB = (N + 4095) / 4096;
  scan1_kernel<<<NB, 256, 0, stream>>>(counts, poffs, bsum, N);

  int QB = (N + 63) / 64;
  int PB = (E + 255) / 256;
  int FB = (N + 255) / 256;
  fused_kernel<<<QB + PB + FB, 256, 0, stream>>>(
      n_id, embtab, memtab, Wt, ball, qb, kb, vb, out, N,
      srcA, dstA, E, poffs, bsum, pos, ssrc, offs, QB, PB);

  attn_kernel<<<(N + 15) / 16, 256, 0, stream>>>(qb, kb, vb, offs, ssrc, out, N);
}